// Round 5
// baseline (696.222 us; speedup 1.0000x reference)
//
#include <hip/hip_runtime.h>
#include <hip/hip_bf16.h>
#include <hip/hip_cooperative_groups.h>

namespace cg = cooperative_groups;

// Voxelization scatter-mean, single cooperative dispatch:
//   phase0 zero hist -> phase1 per-point voxel id + rank (int atomics, L2)
//   -> phase2 per-batch exclusive scan -> phase3 LDS-transpose feat tiles and
//   scatter 256B point-rows to sorted slots (pos = offs + rank, no atomics)
//   -> phase4 per-voxel segmented sum over contiguous rows, normalize,
//   LDS-transpose, coalesced [B][C][R] writes.
// Fallbacks: round-4 coalesced-atomic path, then round-2 CSR path.

#define BB 16
#define CC 64
#define NN 16384
#define XX 38
#define YY 24
#define ZZ 24
#define RR (XX * YY * ZZ)   // 21888
#define SS 21896            // padded per-batch stride (ints)
#define RBLK 86             // ceil(RR/256)
#define NTILES (RR / 64)    // 342
#define GRID 1024           // GRID*256 == BB*NN exactly

__device__ __forceinline__ int voxel_id(const float* coords, int t) {
    float cx = coords[t * 3 + 0];
    float cy = coords[t * 3 + 1];
    float cz = coords[t * 3 + 2];
    // Match reference IEEE ops: floor(c / voxel_size) - min_voxel_coord
    int ix = (int)(floorf(cx / 0.3f) + 19.0f);
    int iy = (int)(floorf(cy / 0.3f) + 12.0f);
    int iz = (int)(floorf(cz / 0.2f) + 12.0f);
    bool valid = (ix >= 0) & (ix < XX) & (iy >= 0) & (iy < YY) &
                 (iz >= 0) & (iz < ZZ);
    return valid ? (ix * (YY * ZZ) + iy * ZZ + iz) : RR;
}

__global__ void __launch_bounds__(256, 4)
vox_coop(const float* feat, const float* coords, float* out,
         int* hist, int* offs, int* vid, int* rank, float* sfeat) {
    cg::grid_group grid = cg::this_grid();
    __shared__ float lt[64][65];     // 16.6 KB transpose/accumulate tile
    __shared__ int ivals[256];       // scan partials / point positions

    int bx = blockIdx.x, tid = threadIdx.x;
    int g = bx * 256 + tid;          // 0 .. B*N-1
    int lane = tid & 63, w = tid >> 6;

    // ---- phase 0: zero hist ----
    for (int i = g; i < BB * SS; i += GRID * 256) hist[i] = 0;
    grid.sync();

    // ---- phase 1: voxel id + rank (one point per thread) ----
    {
        int b = g >> 14;
        int v = voxel_id(coords, g);
        vid[g] = v;
        rank[g] = atomicAdd(&hist[b * SS + v], 1);
    }
    grid.sync();

    // ---- phase 2: exclusive scan, blocks 0..15 (one per batch) ----
    if (bx < BB) {
        const int* h = hist + bx * SS;
        int* o = offs + bx * SS;
        int base = tid * RBLK;
        int end = min(base + RBLK, RR);
        int s = 0;
        for (int i = base; i < end; ++i) s += h[i];
        ivals[tid] = s;
        __syncthreads();
        for (int d = 1; d < 256; d <<= 1) {
            int v2 = (tid >= d) ? ivals[tid - d] : 0;
            __syncthreads();
            ivals[tid] += v2;
            __syncthreads();
        }
        int run = (tid == 0) ? 0 : ivals[tid - 1];
        for (int i = base; i < end; ++i) { o[i] = run; run += h[i]; }
        if (tid == 255) o[RR] = ivals[255];
    }
    grid.sync();

    // ---- phase 3: transpose 64pt x 64ch tiles, scatter sorted 256B rows ----
    for (int tile = bx; tile < BB * (NN / 64); tile += GRID) {   // 4 iters
        int b = tile >> 8;
        int n0 = (tile & 255) * 64;
        if (tid < 64) {
            int t = b * NN + n0 + tid;
            int v = vid[t];
            ivals[tid] = (v < RR) ? (offs[b * SS + v] + rank[t]) : -1;
        }
        const float* fb = feat + (size_t)b * CC * NN;
#pragma unroll
        for (int it = 0; it < 16; ++it) {
            int c = it * 4 + w;
            lt[lane][c] = fb[(size_t)c * NN + n0 + lane];   // 256B coalesced
        }
        __syncthreads();
        float* sb = sfeat + (size_t)b * NN * CC;
#pragma unroll
        for (int i = 0; i < 16; ++i) {
            int p = w * 16 + i;
            int dst = ivals[p];
            if (dst >= 0) sb[(size_t)dst * CC + lane] = lt[p][lane];  // 256B row
        }
        __syncthreads();
    }
    grid.sync();

    // ---- phase 4: segmented sum over sorted rows, normalize, write out ----
    for (int tile = bx; tile < BB * NTILES; tile += GRID) {      // 5-6 iters
        int b = tile / NTILES;
        int r0 = (tile % NTILES) * 64;
        const int* o = offs + b * SS;
        const float* sb = sfeat + (size_t)b * NN * CC;
#pragma unroll
        for (int i = 0; i < 16; ++i) {
            int rl = w * 16 + i;
            int r = r0 + rl;
            int s2 = o[r], e2 = o[r + 1];        // wave-uniform
            float sum = 0.0f;
            for (int j = s2; j < e2; ++j) sum += sb[(size_t)j * CC + lane];
            lt[rl][lane] = sum / (float)max(e2 - s2, 1);
        }
        __syncthreads();
        float* ob = out + (size_t)b * CC * RR;
#pragma unroll
        for (int it = 0; it < 16; ++it) {
            int idx = it * 256 + tid;
            int c = idx >> 6, rr = idx & 63;     // c wave-uniform
            ob[(size_t)c * RR + r0 + rr] = lt[rr][c];       // 256B coalesced
        }
        __syncthreads();
    }
}

// ---------------- fallback 1: round-4 coalesced-atomic path ----------------

__global__ void vox_scatter_t(const float* __restrict__ feat,
                              const float* __restrict__ coords,
                              float* __restrict__ acc,
                              int* __restrict__ cnt) {
    __shared__ float lt[64][65];
    __shared__ int vv[64];
    int blk = blockIdx.x;
    int b = blk >> 8;
    int n0 = (blk & 255) * 64;
    int tid = threadIdx.x;
    int lane = tid & 63, w = tid >> 6;
    if (tid < 64) {
        int v = voxel_id(coords, b * NN + n0 + tid);
        vv[tid] = v;
        if (v < RR) atomicAdd(&cnt[b * RR + v], 1);
    }
    const float* fb = feat + (size_t)b * CC * NN;
#pragma unroll
    for (int it = 0; it < 16; ++it) {
        int c = it * 4 + w;
        lt[lane][c] = fb[(size_t)c * NN + n0 + lane];
    }
    __syncthreads();
#pragma unroll
    for (int i = 0; i < 16; ++i) {
        int p = w * 16 + i;
        int v = vv[p];
        if (v < RR) atomicAdd(&acc[((size_t)b * RR + v) * CC + lane], lt[p][lane]);
    }
}

__global__ void vox_finish(const float* __restrict__ acc,
                           const int* __restrict__ cnt,
                           float* __restrict__ out) {
    __shared__ float lt[64][65];
    int blk = blockIdx.x;
    int b = blk / NTILES;
    int r0 = (blk % NTILES) * 64;
    int tid = threadIdx.x;
    int lane = tid & 63, w = tid >> 6;
#pragma unroll
    for (int i = 0; i < 16; ++i) {
        int rl = w * 16 + i;
        int r = r0 + rl;
        int c_ = cnt[b * RR + r];
        float val = 0.0f;
        if (c_ > 0) val = acc[((size_t)b * RR + r) * CC + lane] / (float)c_;
        lt[rl][lane] = val;
    }
    __syncthreads();
    float* ob = out + (size_t)b * CC * RR;
#pragma unroll
    for (int it = 0; it < 16; ++it) {
        int idx = it * 256 + tid;
        int c = idx >> 6, rr = idx & 63;
        ob[(size_t)c * RR + r0 + rr] = lt[rr][c];
    }
}

// ---------------- fallback 2: round-2 CSR path (~5.9 MB ws) ----------------

__global__ void vox_index_fb(const float* __restrict__ coords,
                             int* __restrict__ hist,
                             int* __restrict__ vidp,
                             int* __restrict__ rankp) {
    int t = blockIdx.x * blockDim.x + threadIdx.x;
    int b = t >> 14;
    int v = voxel_id(coords, t);
    vidp[t] = v;
    rankp[t] = atomicAdd(&hist[b * SS + v], 1);
}

__global__ void vox_scan_fb(const int* __restrict__ hist,
                            int* __restrict__ offs) {
    __shared__ int part[256];
    int b = blockIdx.x;
    const int* h = hist + b * SS;
    int* o = offs + b * SS;
    int t = threadIdx.x;
    int base = t * RBLK;
    int end = min(base + RBLK, RR);
    int s = 0;
    for (int i = base; i < end; ++i) s += h[i];
    part[t] = s;
    __syncthreads();
    for (int d = 1; d < 256; d <<= 1) {
        int v = (t >= d) ? part[t - d] : 0;
        __syncthreads();
        part[t] += v;
        __syncthreads();
    }
    int run = (t == 0) ? 0 : part[t - 1];
    for (int i = base; i < end; ++i) { o[i] = run; run += h[i]; }
    if (t == 255) o[RR] = part[255];
}

__global__ void vox_sort_fb(const int* __restrict__ vidp,
                            const int* __restrict__ rankp,
                            const int* __restrict__ offs,
                            int* __restrict__ sidx) {
    int t = blockIdx.x * blockDim.x + threadIdx.x;
    int b = t >> 14;
    int pos = offs[b * SS + vidp[t]] + rankp[t];
    sidx[b * NN + pos] = t & (NN - 1);
}

__global__ void vox_gather_fb(const float* __restrict__ feat,
                              const int* __restrict__ offs,
                              const int* __restrict__ sidx,
                              float* __restrict__ out) {
    int blk = blockIdx.x;
    int rb = blk % RBLK;
    int bc = blk / RBLK;
    int r = rb * 256 + threadIdx.x;
    if (r >= RR) return;
    int b = bc >> 6;
    const int* o = offs + b * SS;
    int start = o[r], end = o[r + 1];
    const int* si = sidx + b * NN;
    const float* f = feat + (size_t)bc * NN;
    float sum = 0.0f;
    for (int j = start; j < end; ++j) sum += f[si[j]];
    out[(size_t)bc * RR + r] = sum / (float)max(end - start, 1);
}

extern "C" void kernel_launch(void* const* d_in, const int* in_sizes, int n_in,
                              void* d_out, int out_size, void* d_ws, size_t ws_size,
                              hipStream_t stream) {
    const float* feat   = (const float*)d_in[0];   // [B, C, N]
    const float* coords = (const float*)d_in[1];   // [B, N, 3]
    float* out = (float*)d_out;                    // [B, C, X, Y, Z]
    int pts = BB * NN;

    // coop layout: hist, offs, vid, rank (ints) + sfeat (floats)  ~72 MB
    size_t ss = (size_t)BB * SS;
    size_t ints = 2 * ss + 2 * (size_t)pts;
    size_t need_coop = ints * 4 + (size_t)BB * NN * CC * 4;

    if (ws_size >= need_coop) {
        int* hist  = (int*)d_ws;
        int* offs  = hist + ss;
        int* vid   = offs + ss;
        int* rank  = vid + pts;
        float* sfeat = (float*)(rank + pts);
        void* args[] = { (void*)&feat, (void*)&coords, (void*)&out,
                         (void*)&hist, (void*)&offs, (void*)&vid,
                         (void*)&rank, (void*)&sfeat };
        hipError_t err = hipLaunchCooperativeKernel(
            (void*)vox_coop, dim3(GRID), dim3(256), args, 0, stream);
        if (err == hipSuccess) return;
    }

    size_t acc_elems = (size_t)BB * RR * CC;
    size_t need_atomic = (acc_elems + (size_t)BB * RR) * 4;     // ~91.1 MB
    if (ws_size >= need_atomic) {
        float* acc = (float*)d_ws;
        int* cnt = (int*)(acc + acc_elems);
        hipMemsetAsync(d_ws, 0, need_atomic, stream);
        vox_scatter_t<<<BB * (NN / 64), 256, 0, stream>>>(feat, coords, acc, cnt);
        vox_finish<<<BB * NTILES, 256, 0, stream>>>(acc, cnt, out);
    } else {
        int* hist = (int*)d_ws;
        int* offs = hist + ss;
        int* vid  = offs + ss;
        int* rank = vid + pts;
        int* sidx = rank + pts;
        hipMemsetAsync(hist, 0, ss * sizeof(int), stream);
        vox_index_fb<<<pts / 256, 256, 0, stream>>>(coords, hist, vid, rank);
        vox_scan_fb<<<BB, 256, 0, stream>>>(hist, offs);
        vox_sort_fb<<<pts / 256, 256, 0, stream>>>(vid, rank, offs, sidx);
        vox_gather_fb<<<BB * CC * RBLK, 256, 0, stream>>>(feat, offs, sidx, out);
    }
}

// Round 6
// 185.700 us; speedup vs baseline: 3.7492x; 3.7492x over previous
//
#include <hip/hip_runtime.h>
#include <hip/hip_bf16.h>

// Voxelization scatter-mean via PACKED-BF16 coalesced atomics:
//   acc is bf16 [B][R][64] (128 B/row = 2 cache lines/point, vs 4 for fp32)
//   -> halves the L2 atomic line-RMW count, which is the measured invariant
//   (~18.5 line-RMWs/ns across rounds 1 and 4).
//   1) memset cnt+acc (46 MB)
//   2) vox_scatter_pk: LDS-transpose 64pt x 64ch feat tiles; per point one
//      half-wave (32-lane) global_atomic_pk_add_bf16 row-add + 1 cnt atomic
//   3) vox_finish_pk: cnt-guarded bf16 row read, unpack, normalize, LDS
//      transpose, coalesced fp32 [B][C][R] writes
// Precision: out = bf16_sum / cnt; error <= ulp(|sum|)/2/cnt + input rounding
// ~<= 0.05 << 0.108 threshold.
// Fallback (small ws): round-4 fp32-atomic path.

#define BB 16
#define CC 64
#define NN 16384
#define XX 38
#define YY 24
#define ZZ 24
#define RR (XX * YY * ZZ)   // 21888
#define NTILES (RR / 64)    // 342

__device__ __forceinline__ int voxel_id(const float* __restrict__ coords, int t) {
    float cx = coords[t * 3 + 0];
    float cy = coords[t * 3 + 1];
    float cz = coords[t * 3 + 2];
    // Match reference IEEE ops: floor(c / voxel_size) - min_voxel_coord
    int ix = (int)(floorf(cx / 0.3f) + 19.0f);
    int iy = (int)(floorf(cy / 0.3f) + 12.0f);
    int iz = (int)(floorf(cz / 0.2f) + 12.0f);
    bool valid = (ix >= 0) & (ix < XX) & (iy >= 0) & (iy < YY) &
                 (iz >= 0) & (iz < ZZ);
    return valid ? (ix * (YY * ZZ) + iy * ZZ + iz) : RR;
}

__device__ __forceinline__ unsigned int pack2_bf16_rne(float a, float b) {
    unsigned int ua = __float_as_uint(a), ub = __float_as_uint(b);
    ua = (ua + 0x7fffu + ((ua >> 16) & 1u)) >> 16;   // round-nearest-even
    ub = (ub + 0x7fffu + ((ub >> 16) & 1u)) >> 16;
    return ua | (ub << 16);
}

// Block = 64 points x 64 channels (4 waves). Coalesced feat read, LDS
// transpose; per point a 32-lane pk-bf16 atomic row-add (2 lines).
__global__ void vox_scatter_pk(const float* __restrict__ feat,
                               const float* __restrict__ coords,
                               unsigned short* __restrict__ acc,  // bf16 [B][R][64]
                               int* __restrict__ cnt) {
    __shared__ float lt[64][66];     // stride 66 keeps float2 reads 8B-aligned
    __shared__ int vv[64];
    int blk = blockIdx.x;            // B * (N/64) = 4096
    int b = blk >> 8;
    int n0 = (blk & 255) * 64;
    int tid = threadIdx.x;
    int lane = tid & 63, w = tid >> 6;

    if (tid < 64) {
        int v = voxel_id(coords, b * NN + n0 + tid);
        vv[tid] = v;
        if (v < RR) atomicAdd(&cnt[b * RR + v], 1);
    }

    const float* fb = feat + (size_t)b * CC * NN;
#pragma unroll
    for (int it = 0; it < 16; ++it) {
        int c = it * 4 + w;
        lt[lane][c] = fb[(size_t)c * NN + n0 + lane];   // 256B coalesced
    }
    __syncthreads();

    int half = lane >> 5, l = lane & 31;   // half-wave handles one point
#pragma unroll
    for (int i = 0; i < 8; ++i) {
        int p = w * 16 + i * 2 + half;
        int v = vv[p];
        if (v < RR) {
            float2 ab = *(const float2*)&lt[p][2 * l];
            unsigned int pk = pack2_bf16_rne(ab.x, ab.y);
            unsigned long long addr = (unsigned long long)acc +
                ((size_t)b * RR + v) * 128ull + 4ull * l;   // 32 lanes: 128B row
            asm volatile("global_atomic_pk_add_bf16 %0, %1, off"
                         :: "v"(addr), "v"(pk) : "memory");
        }
    }
}

// Block = 64 voxels x 64 channels. cnt-guarded bf16 row read, normalize,
// LDS transpose, coalesced fp32 [B][C][R] writes.
__global__ void vox_finish_pk(const unsigned short* __restrict__ acc,
                              const int* __restrict__ cnt,
                              float* __restrict__ out) {
    __shared__ float lt[64][65];
    int blk = blockIdx.x;            // B * NTILES = 5472
    int b = blk / NTILES;
    int r0 = (blk % NTILES) * 64;
    int tid = threadIdx.x;
    int lane = tid & 63, w = tid >> 6;

#pragma unroll
    for (int i = 0; i < 16; ++i) {
        int rl = w * 16 + i;
        int r = r0 + rl;
        int c_ = cnt[b * RR + r];                        // wave-scalar
        float val = 0.0f;
        if (c_ > 0) {
            unsigned short h = acc[((size_t)b * RR + r) * 64 + lane];  // 128B row
            val = __uint_as_float((unsigned int)h << 16) / (float)c_;
        }
        lt[rl][lane] = val;
    }
    __syncthreads();

    float* ob = out + (size_t)b * CC * RR;
#pragma unroll
    for (int it = 0; it < 16; ++it) {
        int idx = it * 256 + tid;
        int c = idx >> 6, rr = idx & 63;                 // c wave-uniform
        ob[(size_t)c * RR + r0 + rr] = lt[rr][c];        // 256B coalesced
    }
}

// ---------------- fallback: round-4 fp32-atomic path ----------------

__global__ void vox_scatter_t(const float* __restrict__ feat,
                              const float* __restrict__ coords,
                              float* __restrict__ acc,
                              int* __restrict__ cnt) {
    __shared__ float lt[64][65];
    __shared__ int vv[64];
    int blk = blockIdx.x;
    int b = blk >> 8;
    int n0 = (blk & 255) * 64;
    int tid = threadIdx.x;
    int lane = tid & 63, w = tid >> 6;
    if (tid < 64) {
        int v = voxel_id(coords, b * NN + n0 + tid);
        vv[tid] = v;
        if (v < RR) atomicAdd(&cnt[b * RR + v], 1);
    }
    const float* fb = feat + (size_t)b * CC * NN;
#pragma unroll
    for (int it = 0; it < 16; ++it) {
        int c = it * 4 + w;
        lt[lane][c] = fb[(size_t)c * NN + n0 + lane];
    }
    __syncthreads();
#pragma unroll
    for (int i = 0; i < 16; ++i) {
        int p = w * 16 + i;
        int v = vv[p];
        if (v < RR) atomicAdd(&acc[((size_t)b * RR + v) * CC + lane], lt[p][lane]);
    }
}

__global__ void vox_finish(const float* __restrict__ acc,
                           const int* __restrict__ cnt,
                           float* __restrict__ out) {
    __shared__ float lt[64][65];
    int blk = blockIdx.x;
    int b = blk / NTILES;
    int r0 = (blk % NTILES) * 64;
    int tid = threadIdx.x;
    int lane = tid & 63, w = tid >> 6;
#pragma unroll
    for (int i = 0; i < 16; ++i) {
        int rl = w * 16 + i;
        int r = r0 + rl;
        int c_ = cnt[b * RR + r];
        float val = 0.0f;
        if (c_ > 0) val = acc[((size_t)b * RR + r) * CC + lane] / (float)c_;
        lt[rl][lane] = val;
    }
    __syncthreads();
    float* ob = out + (size_t)b * CC * RR;
#pragma unroll
    for (int it = 0; it < 16; ++it) {
        int idx = it * 256 + tid;
        int c = idx >> 6, rr = idx & 63;
        ob[(size_t)c * RR + r0 + rr] = lt[rr][c];
    }
}

extern "C" void kernel_launch(void* const* d_in, const int* in_sizes, int n_in,
                              void* d_out, int out_size, void* d_ws, size_t ws_size,
                              hipStream_t stream) {
    const float* feat   = (const float*)d_in[0];   // [B, C, N]
    const float* coords = (const float*)d_in[1];   // [B, N, 3]
    float* out = (float*)d_out;                    // [B, C, X, Y, Z]

    size_t cnt_bytes = (size_t)BB * RR * sizeof(int);          // 1.40 MB
    size_t acc_pk_bytes = (size_t)BB * RR * 64 * 2;            // 44.8 MB bf16
    size_t need_pk = cnt_bytes + acc_pk_bytes;                 // 46.2 MB

    if (ws_size >= need_pk) {
        int* cnt = (int*)d_ws;
        unsigned short* acc = (unsigned short*)((char*)d_ws + cnt_bytes);

        hipMemsetAsync(d_ws, 0, need_pk, stream);
        vox_scatter_pk<<<BB * (NN / 64), 256, 0, stream>>>(feat, coords, acc, cnt);
        vox_finish_pk<<<BB * NTILES, 256, 0, stream>>>(acc, cnt, out);
        return;
    }

    size_t acc_elems = (size_t)BB * RR * CC;
    size_t need_f32 = (acc_elems + (size_t)BB * RR) * 4;       // ~91.1 MB
    if (ws_size >= need_f32) {
        float* acc = (float*)d_ws;
        int* cnt = (int*)(acc + acc_elems);
        hipMemsetAsync(d_ws, 0, need_f32, stream);
        vox_scatter_t<<<BB * (NN / 64), 256, 0, stream>>>(feat, coords, acc, cnt);
        vox_finish<<<BB * NTILES, 256, 0, stream>>>(acc, cnt, out);
    }
}